// Round 14
// baseline (122.643 us; speedup 1.0000x reference)
//
#include <hip/hip_runtime.h>
#include <hip/hip_bf16.h>

typedef __attribute__((ext_vector_type(8))) short short8v;
typedef __attribute__((ext_vector_type(4))) float f32x4;

#define L_SEQ 2048
#define D_DIM 1024
#define N_DIM 16
#define T_CHUNK 32
#define NCHUNK (L_SEQ / T_CHUNK)  // 64
#define EPS_DISC 1e-9f

__device__ __forceinline__ float softplusf(float x) {
    return (x > 15.f) ? x : __logf(1.f + __expf(x));
}

__device__ __forceinline__ unsigned short f2bf(float f) {
    unsigned int u = __float_as_uint(f);
    u += 0x7FFFu + ((u >> 16) & 1u);   // RNE
    return (unsigned short)(u >> 16);
}
__device__ __forceinline__ unsigned int pack2(float a, float b) {
    return (unsigned int)f2bf(a) | ((unsigned int)f2bf(b) << 16);
}
__device__ __forceinline__ float dot4(float4 a, float4 b) {
    return a.x * b.x + a.y * b.y + a.z * b.z + a.w * b.w;
}
__device__ __forceinline__ float dot4v(f32x4 a, f32x4 b) {
    return a.x * b.x + a.y * b.y + a.z * b.z + a.w * b.w;
}

// 16-byte async global->LDS DMA (per lane: writes lds_base + lane*16)
__device__ __forceinline__ void gll16(const float* g, float* lds) {
    __builtin_amdgcn_global_load_lds(
        (const __attribute__((address_space(1))) unsigned int*)g,
        (__attribute__((address_space(3))) unsigned int*)lds,
        16, 0, 0);
}

// ============ K_A: fused params — mv FIRST so the stream ramps immediately ===
// blocks [0,1024)    : h0 matvec slabs (DMA double-buffered), XCD-swizzled
// blocks [1024,1280) : dt GEMM (arrives ~20us in, hides inside the stream)
// blocks [1280,1536) : B/C GEMV
__global__ __launch_bounds__(256) void k_params(const float* __restrict__ u,
                                                const float* __restrict__ dt_w,
                                                const float* __restrict__ dt_b,
                                                const float* __restrict__ B_w,
                                                const float* __restrict__ B_b,
                                                const float* __restrict__ C_w,
                                                const float* __restrict__ C_b,
                                                const float* __restrict__ init_w,
                                                const float* __restrict__ init_b,
                                                float* __restrict__ dt,
                                                float* __restrict__ Bm,
                                                float* __restrict__ Cm,
                                                float* __restrict__ h0) {
    __shared__ __align__(16) float smem_f[11392];   // 45.5 KB, aliased per branch
    const int b = blockIdx.x;
    const int t = threadIdx.x;

    if (b < 1024) {
        // ---- h0 matvec slab: 16 rows x 3072, DMA-staged ----
        // XCD-bijective swizzle: XCD j (= b%8) gets contiguous slabs j*128..
        const int slab = (b & 7) * 128 + (b >> 3);   // 0..1023, bijective
        const int wv = t >> 6, lane = t & 63;
        float* u_lds = smem_f;                       // 3072 floats
        float* wbuf0 = smem_f + 3072;                // 16 rows x 260f
        float* wbuf1 = smem_f + 3072 + 4160;

        // prologue: stage u (3 glls/wave) + chunk 0 (4 glls/wave)
#pragma unroll
        for (int i = 0; i < 3; ++i) {
            const int idx = wv * 3 + i;
            gll16(u + idx * 256 + lane * 4, u_lds + idx * 256);
        }
#pragma unroll
        for (int j = 0; j < 4; ++j) {
            const int r = wv * 4 + j;
            gll16(init_w + (size_t)(slab * 16 + r) * 3072 + lane * 4,
                  wbuf0 + r * 260);
        }

        float acc = 0.f;
        const int r = t >> 4;                        // row 0..15
        const int g = t & 15;                        // 16 threads per row

#pragma unroll 1
        for (int c = 0; c < 12; ++c) {
            if (c < 11) {
                float* nb = ((c + 1) & 1) ? wbuf1 : wbuf0;
#pragma unroll
                for (int j = 0; j < 4; ++j) {
                    const int rr = wv * 4 + j;
                    gll16(init_w + (size_t)(slab * 16 + rr) * 3072 + (c + 1) * 256 + lane * 4,
                          nb + rr * 260);
                }
                asm volatile("s_waitcnt vmcnt(4)" ::: "memory");
            } else {
                asm volatile("s_waitcnt vmcnt(0)" ::: "memory");
            }
            __builtin_amdgcn_s_barrier();

            const float* wb = ((c & 1) ? wbuf1 : wbuf0) + r * 260;
            const float* ub = u_lds + c * 256;
#pragma unroll
            for (int it = 0; it < 4; ++it) {
                const int ks = g * 4 + it * 64;
                f32x4 wv4 = *(const f32x4*)&wb[ks];
                f32x4 uv4 = *(const f32x4*)&ub[ks];
                acc += dot4v(wv4, uv4);
            }
            asm volatile("" ::: "memory");
            __builtin_amdgcn_s_barrier();
        }

#pragma unroll
        for (int m = 8; m >= 1; m >>= 1) acc += __shfl_xor(acc, m, 16);
        if (g == 0) {
            const int row = slab * 16 + r;
            h0[row] = acc + init_b[row];
        }
    } else if (b < 1280) {
        // ---- dt GEMM tile: BM=64 x BN=128 x BK=32, bf16 MFMA ----
        unsigned int* As = (unsigned int*)smem_f;        // 64*16
        unsigned int* Bs = (unsigned int*)smem_f + 1024; // 128*16
        const int tile = b - 1024;
        const int bm = tile & 31;
        const int bn = tile >> 5;
        const int lane = t & 63;
        const int wn   = t >> 6;
        const int lrow = lane & 15, lq = lane >> 4;

        const int arow = t >> 2, aq = t & 3;
        const int brow = t >> 1, bhalf = t & 1;

        const float* uptr = u + (bm * 64 + arow) * 1024 + aq * 8;
        const float* wptr = dt_w + (bn * 128 + brow) * 1024 + bhalf * 16;

        f32x4 acc[4][2];
#pragma unroll
        for (int mi = 0; mi < 4; ++mi)
#pragma unroll
            for (int ni = 0; ni < 2; ++ni) acc[mi][ni] = (f32x4){0.f, 0.f, 0.f, 0.f};

        for (int k0 = 0; k0 < 1024; k0 += 32) {
            __syncthreads();
            {
                const float4* p = (const float4*)(uptr + k0);
                float4 a0 = p[0], a1 = p[1];
                uint4 ca = make_uint4(pack2(a0.x, a0.y), pack2(a0.z, a0.w),
                                      pack2(a1.x, a1.y), pack2(a1.z, a1.w));
                const int akb = aq ^ ((arow >> 1) & 3);
                *(uint4*)&As[arow * 16 + akb * 4] = ca;

                const float4* q = (const float4*)(wptr + k0);
                float4 b0 = q[0], b1 = q[1], b2 = q[2], b3 = q[3];
                uint4 d0 = make_uint4(pack2(b0.x, b0.y), pack2(b0.z, b0.w),
                                      pack2(b1.x, b1.y), pack2(b1.z, b1.w));
                uint4 d1 = make_uint4(pack2(b2.x, b2.y), pack2(b2.z, b2.w),
                                      pack2(b3.x, b3.y), pack2(b3.z, b3.w));
                const int bswz = (brow >> 1) & 3;
                const int kb0 = (bhalf * 2) ^ bswz, kb1 = (bhalf * 2 + 1) ^ bswz;
                *(uint4*)&Bs[brow * 16 + kb0 * 4] = d0;
                *(uint4*)&Bs[brow * 16 + kb1 * 4] = d1;
            }
            __syncthreads();
            short8v af[4], bf[2];
#pragma unroll
            for (int mi = 0; mi < 4; ++mi) {
                const int ar = mi * 16 + lrow;
                const int kb = lq ^ ((ar >> 1) & 3);
                af[mi] = *(const short8v*)&As[ar * 16 + kb * 4];
            }
#pragma unroll
            for (int ni = 0; ni < 2; ++ni) {
                const int br = wn * 32 + ni * 16 + lrow;
                const int kb = lq ^ ((br >> 1) & 3);
                bf[ni] = *(const short8v*)&Bs[br * 16 + kb * 4];
            }
#pragma unroll
            for (int mi = 0; mi < 4; ++mi)
#pragma unroll
                for (int ni = 0; ni < 2; ++ni)
                    acc[mi][ni] = __builtin_amdgcn_mfma_f32_16x16x32_bf16(af[mi], bf[ni], acc[mi][ni], 0, 0, 0);
        }

#pragma unroll
        for (int mi = 0; mi < 4; ++mi)
#pragma unroll
            for (int ni = 0; ni < 2; ++ni) {
                const int cg = bn * 128 + wn * 32 + ni * 16 + lrow;
                const float bv = dt_b[cg];
#pragma unroll
                for (int j = 0; j < 4; ++j) {
                    const int rg = bm * 64 + mi * 16 + lq * 4 + j;
                    dt[rg * 1024 + cg] = softplusf(acc[mi][ni][j] + bv);
                }
            }
    } else {
        // ---- B/C GEMV: 8 rows/block, 2 rows/wave ----
        const int s2 = b - 1280;
        const int wv = t >> 6, lane = t & 63;
#pragma unroll
        for (int rep = 0; rep < 2; ++rep) {
            const int l = s2 * 8 + wv * 2 + rep;
            const float4* u4 = (const float4*)(u + l * 1024);
            float4 ur[4];
#pragma unroll
            for (int i = 0; i < 4; ++i) ur[i] = u4[i * 64 + lane];
#pragma unroll 4
            for (int c = 0; c < 32; ++c) {
                const float4* wr = (const float4*)((c < 16) ? (B_w + c * 1024)
                                                            : (C_w + (c - 16) * 1024));
                float sv = 0.f;
#pragma unroll
                for (int i = 0; i < 4; ++i) sv += dot4(ur[i], wr[i * 64 + lane]);
#pragma unroll
                for (int off = 32; off > 0; off >>= 1) sv += __shfl_down(sv, off);
                if (lane == 0) {
                    if (c < 16) Bm[l * 16 + c] = sv + B_b[c];
                    else        Cm[l * 16 + (c - 16)] = sv + C_b[c - 16];
                }
            }
        }
    }
}

// ============ K_P1: per-chunk (prod dA, local h with h_in=0) =================
__global__ __launch_bounds__(256) void k_p1(const float* __restrict__ dt,
                                            const float* __restrict__ Bm,
                                            const float* __restrict__ u,
                                            const float* __restrict__ A_log,
                                            float* __restrict__ ap,
                                            float* __restrict__ hl) {
    const int t    = threadIdx.x;
    const int c    = blockIdx.x >> 3;
    const int dblk = blockIdx.x & 7;
    const int dd   = t >> 1;
    const int nh   = t & 1;
    const int d    = dblk * 128 + dd;
    float An[8];
#pragma unroll
    for (int n = 0; n < 8; ++n) An[n] = -__expf(A_log[nh * 8 + n]);
    float h[8], p[8];
#pragma unroll
    for (int n = 0; n < 8; ++n) { h[n] = 0.f; p[n] = 1.f; }

    const int l0 = c * T_CHUNK;
    for (int i = 0; i < T_CHUNK; ++i) {
        const int l = l0 + i;
        const float dtld = dt[l * D_DIM + d];
        const float uld  = u[l * D_DIM + d];
        const float4 b0 = *(const float4*)&Bm[l * 16 + nh * 8];
        const float4 b1 = *(const float4*)&Bm[l * 16 + nh * 8 + 4];
        auto body = [&](int n, float bn) {
            const float x = dtld * An[n];
            const float e = __expf(x);
            const float coef = (e - 1.f) * __builtin_amdgcn_rcpf(x + EPS_DISC);
            const float bu = coef * bn * uld;
            p[n] *= e;
            h[n] = fmaf(e, h[n], bu);
        };
        body(0, b0.x); body(1, b0.y); body(2, b0.z); body(3, b0.w);
        body(4, b1.x); body(5, b1.y); body(6, b1.z); body(7, b1.w);
    }
    const int base = c * (D_DIM * N_DIM) + d * 16 + nh * 8;
    *(float4*)&ap[base + 0] = make_float4(p[0], p[1], p[2], p[3]);
    *(float4*)&ap[base + 4] = make_float4(p[4], p[5], p[6], p[7]);
    *(float4*)&hl[base + 0] = make_float4(h[0], h[1], h[2], h[3]);
    *(float4*)&hl[base + 4] = make_float4(h[4], h[5], h[6], h[7]);
}

// ============ K_P2: chunk-level scan (64 steps) ==============================
__global__ __launch_bounds__(64) void k_p2(const float* __restrict__ h0,
                                           float* __restrict__ ap,
                                           const float* __restrict__ hl) {
    const int ch = blockIdx.x * 64 + threadIdx.x;
    float h = h0[ch];
#pragma unroll 8
    for (int c = 0; c < NCHUNK; ++c) {
        const int idx = c * (D_DIM * N_DIM) + ch;
        const float a = ap[idx];
        const float b = hl[idx];
        ap[idx] = h;
        h = fmaf(a, h, b);
    }
}

// ============ K_P3: recompute with carry-in, fused epilogue ==================
__global__ __launch_bounds__(256) void k_p3(const float* __restrict__ dt,
                                            const float* __restrict__ Bm,
                                            const float* __restrict__ Cm,
                                            const float* __restrict__ u,
                                            const float* __restrict__ A_log,
                                            const float* __restrict__ hstart,
                                            const float* __restrict__ D_w,
                                            const float* __restrict__ scale,
                                            float* __restrict__ out) {
    const int t    = threadIdx.x;
    const int c    = blockIdx.x >> 3;
    const int dblk = blockIdx.x & 7;
    const int dd   = t >> 1;
    const int nh   = t & 1;
    const int d    = dblk * 128 + dd;
    float An[8];
#pragma unroll
    for (int n = 0; n < 8; ++n) An[n] = -__expf(A_log[nh * 8 + n]);
    float h[8];
    const int base = c * (D_DIM * N_DIM) + d * 16 + nh * 8;
    {
        float4 h0v = *(const float4*)&hstart[base + 0];
        float4 h1v = *(const float4*)&hstart[base + 4];
        h[0] = h0v.x; h[1] = h0v.y; h[2] = h0v.z; h[3] = h0v.w;
        h[4] = h1v.x; h[5] = h1v.y; h[6] = h1v.z; h[7] = h1v.w;
    }
    const float scl = fmaxf(scale[0], 0.5f);
    const float dw = D_w[d];
    const int l0 = c * T_CHUNK;
    for (int i = 0; i < T_CHUNK; ++i) {
        const int l = l0 + i;
        const float dtld = dt[l * D_DIM + d];
        const float uld  = u[l * D_DIM + d];
        const float4 b0 = *(const float4*)&Bm[l * 16 + nh * 8];
        const float4 b1 = *(const float4*)&Bm[l * 16 + nh * 8 + 4];
        const float4 c0 = *(const float4*)&Cm[l * 16 + nh * 8];
        const float4 c1 = *(const float4*)&Cm[l * 16 + nh * 8 + 4];
        float y = 0.f;
        auto body = [&](int n, float bn, float cn) {
            const float x = dtld * An[n];
            const float e = __expf(x);
            const float coef = (e - 1.f) * __builtin_amdgcn_rcpf(x + EPS_DISC);
            const float bu = coef * bn * uld;
            h[n] = fmaf(e, h[n], bu);
            y = fmaf(cn, h[n], y);
        };
        body(0, b0.x, c0.x); body(1, b0.y, c0.y); body(2, b0.z, c0.z); body(3, b0.w, c0.w);
        body(4, b1.x, c1.x); body(5, b1.y, c1.y); body(6, b1.z, c1.z); body(7, b1.w, c1.w);
        y += __shfl_xor(y, 1);
        if (nh == 0) {
            const float yv = fmaf(dw, uld, y);
            out[l * D_DIM + d] = softplusf(yv) * scl;
        }
    }
}

extern "C" void kernel_launch(void* const* d_in, const int* in_sizes, int n_in,
                              void* d_out, int out_size, void* d_ws, size_t ws_size,
                              hipStream_t stream) {
    const float* u      = (const float*)d_in[0];
    const float* A_log  = (const float*)d_in[1];
    const float* dt_w   = (const float*)d_in[2];
    const float* dt_b   = (const float*)d_in[3];
    const float* B_w    = (const float*)d_in[4];
    const float* B_b    = (const float*)d_in[5];
    const float* C_w    = (const float*)d_in[6];
    const float* C_b    = (const float*)d_in[7];
    const float* D_w    = (const float*)d_in[8];
    const float* scale  = (const float*)d_in[9];
    const float* init_w = (const float*)d_in[10];
    const float* init_b = (const float*)d_in[11];
    float* out = (float*)d_out;

    float* ws = (float*)d_ws;
    float* dt = ws;                        // 2048*1024 = 2097152
    float* Bm = dt + 2097152;              // 32768
    float* Cm = Bm + 32768;                // 32768
    float* h0 = Cm + 32768;                // 16384
    float* ap = h0 + 16384;                // 64*16384 = 1048576
    float* hl = ap + 1048576;              // 1048576

    hipLaunchKernelGGL(k_params, dim3(1536), dim3(256), 0, stream,
                       u, dt_w, dt_b, B_w, B_b, C_w, C_b, init_w, init_b,
                       dt, Bm, Cm, h0);
    hipLaunchKernelGGL(k_p1, dim3(512), dim3(256), 0, stream, dt, Bm, u, A_log, ap, hl);
    hipLaunchKernelGGL(k_p2, dim3(256), dim3(64), 0, stream, h0, ap, hl);
    hipLaunchKernelGGL(k_p3, dim3(512), dim3(256), 0, stream, dt, Bm, Cm, u, A_log, ap, D_w, scale, out);
}

// Round 15
// 111.135 us; speedup vs baseline: 1.1036x; 1.1036x over previous
//
#include <hip/hip_runtime.h>
#include <hip/hip_bf16.h>

typedef __attribute__((ext_vector_type(8))) short short8v;
typedef __attribute__((ext_vector_type(4))) float f32x4;

#define L_SEQ 2048
#define D_DIM 1024
#define N_DIM 16
#define T_CHUNK 32
#define NCHUNK (L_SEQ / T_CHUNK)  // 64
#define EPS_DISC 1e-9f

__device__ __forceinline__ float softplusf(float x) {
    return (x > 15.f) ? x : __logf(1.f + __expf(x));
}

__device__ __forceinline__ unsigned short f2bf(float f) {
    unsigned int u = __float_as_uint(f);
    u += 0x7FFFu + ((u >> 16) & 1u);   // RNE
    return (unsigned short)(u >> 16);
}
__device__ __forceinline__ unsigned int pack2(float a, float b) {
    return (unsigned int)f2bf(a) | ((unsigned int)f2bf(b) << 16);
}
__device__ __forceinline__ float dot4(float4 a, float4 b) {
    return a.x * b.x + a.y * b.y + a.z * b.z + a.w * b.w;
}
__device__ __forceinline__ float dot4v(f32x4 a, f32x4 b) {
    return a.x * b.x + a.y * b.y + a.z * b.z + a.w * b.w;
}

// 16-byte async global->LDS DMA (per lane: writes lds_base + lane*16)
__device__ __forceinline__ void gll16(const float* g, float* lds) {
    __builtin_amdgcn_global_load_lds(
        (const __attribute__((address_space(1))) unsigned int*)g,
        (__attribute__((address_space(3))) unsigned int*)lds,
        16, 0, 0);
}

// ============ K_A: fused params (R11 best config: gemm, bc, mv; no swizzle) ==
// blocks [0,256)    : dt GEMM, BM=64 x BN=128 x BK=32 (bf16 MFMA)
// blocks [256,512)  : B/C GEMV (coalesced, wave-per-row)
// blocks [512,1536) : h0 matvec — global_load_lds double-buffered staging.
// With ~3 blocks/CU resident, the first wave of blocks already mixes all three
// kinds, so the HBM stream and MFMA work co-schedule from t=0.
__global__ __launch_bounds__(256) void k_params(const float* __restrict__ u,
                                                const float* __restrict__ dt_w,
                                                const float* __restrict__ dt_b,
                                                const float* __restrict__ B_w,
                                                const float* __restrict__ B_b,
                                                const float* __restrict__ C_w,
                                                const float* __restrict__ C_b,
                                                const float* __restrict__ init_w,
                                                const float* __restrict__ init_b,
                                                float* __restrict__ dt,
                                                float* __restrict__ Bm,
                                                float* __restrict__ Cm,
                                                float* __restrict__ h0) {
    __shared__ __align__(16) float smem_f[11392];   // 45.5 KB, aliased per branch
    const int b = blockIdx.x;
    const int t = threadIdx.x;

    if (b < 256) {
        // ---- dt GEMM tile ----
        unsigned int* As = (unsigned int*)smem_f;        // 64*16
        unsigned int* Bs = (unsigned int*)smem_f + 1024; // 128*16
        const int bm = b & 31;
        const int bn = b >> 5;
        const int lane = t & 63;
        const int wn   = t >> 6;
        const int lrow = lane & 15, lq = lane >> 4;

        const int arow = t >> 2, aq = t & 3;
        const int brow = t >> 1, bhalf = t & 1;

        const float* uptr = u + (bm * 64 + arow) * 1024 + aq * 8;
        const float* wptr = dt_w + (bn * 128 + brow) * 1024 + bhalf * 16;

        f32x4 acc[4][2];
#pragma unroll
        for (int mi = 0; mi < 4; ++mi)
#pragma unroll
            for (int ni = 0; ni < 2; ++ni) acc[mi][ni] = (f32x4){0.f, 0.f, 0.f, 0.f};

        for (int k0 = 0; k0 < 1024; k0 += 32) {
            __syncthreads();
            {
                const float4* p = (const float4*)(uptr + k0);
                float4 a0 = p[0], a1 = p[1];
                uint4 ca = make_uint4(pack2(a0.x, a0.y), pack2(a0.z, a0.w),
                                      pack2(a1.x, a1.y), pack2(a1.z, a1.w));
                const int akb = aq ^ ((arow >> 1) & 3);
                *(uint4*)&As[arow * 16 + akb * 4] = ca;

                const float4* q = (const float4*)(wptr + k0);
                float4 b0 = q[0], b1 = q[1], b2 = q[2], b3 = q[3];
                uint4 d0 = make_uint4(pack2(b0.x, b0.y), pack2(b0.z, b0.w),
                                      pack2(b1.x, b1.y), pack2(b1.z, b1.w));
                uint4 d1 = make_uint4(pack2(b2.x, b2.y), pack2(b2.z, b2.w),
                                      pack2(b3.x, b3.y), pack2(b3.z, b3.w));
                const int bswz = (brow >> 1) & 3;
                const int kb0 = (bhalf * 2) ^ bswz, kb1 = (bhalf * 2 + 1) ^ bswz;
                *(uint4*)&Bs[brow * 16 + kb0 * 4] = d0;
                *(uint4*)&Bs[brow * 16 + kb1 * 4] = d1;
            }
            __syncthreads();
            short8v af[4], bf[2];
#pragma unroll
            for (int mi = 0; mi < 4; ++mi) {
                const int ar = mi * 16 + lrow;
                const int kb = lq ^ ((ar >> 1) & 3);
                af[mi] = *(const short8v*)&As[ar * 16 + kb * 4];
            }
#pragma unroll
            for (int ni = 0; ni < 2; ++ni) {
                const int br = wn * 32 + ni * 16 + lrow;
                const int kb = lq ^ ((br >> 1) & 3);
                bf[ni] = *(const short8v*)&Bs[br * 16 + kb * 4];
            }
#pragma unroll
            for (int mi = 0; mi < 4; ++mi)
#pragma unroll
                for (int ni = 0; ni < 2; ++ni)
                    acc[mi][ni] = __builtin_amdgcn_mfma_f32_16x16x32_bf16(af[mi], bf[ni], acc[mi][ni], 0, 0, 0);
        }

#pragma unroll
        for (int mi = 0; mi < 4; ++mi)
#pragma unroll
            for (int ni = 0; ni < 2; ++ni) {
                const int cg = bn * 128 + wn * 32 + ni * 16 + lrow;
                const float bv = dt_b[cg];
#pragma unroll
                for (int j = 0; j < 4; ++j) {
                    const int rg = bm * 64 + mi * 16 + lq * 4 + j;
                    dt[rg * 1024 + cg] = softplusf(acc[mi][ni][j] + bv);
                }
            }
    } else if (b < 512) {
        // ---- B/C GEMV: 8 rows/block, 2 rows/wave ----
        const int s2 = b - 256;
        const int wv = t >> 6, lane = t & 63;
#pragma unroll
        for (int rep = 0; rep < 2; ++rep) {
            const int l = s2 * 8 + wv * 2 + rep;
            const float4* u4 = (const float4*)(u + l * 1024);
            float4 ur[4];
#pragma unroll
            for (int i = 0; i < 4; ++i) ur[i] = u4[i * 64 + lane];
#pragma unroll 4
            for (int c = 0; c < 32; ++c) {
                const float4* wr = (const float4*)((c < 16) ? (B_w + c * 1024)
                                                            : (C_w + (c - 16) * 1024));
                float sv = 0.f;
#pragma unroll
                for (int i = 0; i < 4; ++i) sv += dot4(ur[i], wr[i * 64 + lane]);
#pragma unroll
                for (int off = 32; off > 0; off >>= 1) sv += __shfl_down(sv, off);
                if (lane == 0) {
                    if (c < 16) Bm[l * 16 + c] = sv + B_b[c];
                    else        Cm[l * 16 + (c - 16)] = sv + C_b[c - 16];
                }
            }
        }
    } else {
        // ---- h0 matvec slab: 16 rows x 3072, DMA-staged ----
        const int slab = b - 512;                    // 0..1023
        const int wv = t >> 6, lane = t & 63;
        float* u_lds = smem_f;                       // 3072 floats
        float* wbuf0 = smem_f + 3072;                // 16 rows x 260f
        float* wbuf1 = smem_f + 3072 + 4160;

        // prologue: stage u (3 glls/wave) + chunk 0 (4 glls/wave)
#pragma unroll
        for (int i = 0; i < 3; ++i) {
            const int idx = wv * 3 + i;
            gll16(u + idx * 256 + lane * 4, u_lds + idx * 256);
        }
#pragma unroll
        for (int j = 0; j < 4; ++j) {
            const int r = wv * 4 + j;
            gll16(init_w + (size_t)(slab * 16 + r) * 3072 + lane * 4,
                  wbuf0 + r * 260);
        }

        float acc = 0.f;
        const int r = t >> 4;                        // row 0..15
        const int g = t & 15;                        // 16 threads per row

#pragma unroll 1
        for (int c = 0; c < 12; ++c) {
            if (c < 11) {
                float* nb = ((c + 1) & 1) ? wbuf1 : wbuf0;
#pragma unroll
                for (int j = 0; j < 4; ++j) {
                    const int rr = wv * 4 + j;
                    gll16(init_w + (size_t)(slab * 16 + rr) * 3072 + (c + 1) * 256 + lane * 4,
                          nb + rr * 260);
                }
                asm volatile("s_waitcnt vmcnt(4)" ::: "memory");
            } else {
                asm volatile("s_waitcnt vmcnt(0)" ::: "memory");
            }
            __builtin_amdgcn_s_barrier();

            const float* wb = ((c & 1) ? wbuf1 : wbuf0) + r * 260;
            const float* ub = u_lds + c * 256;
#pragma unroll
            for (int it = 0; it < 4; ++it) {
                const int ks = g * 4 + it * 64;
                f32x4 wv4 = *(const f32x4*)&wb[ks];
                f32x4 uv4 = *(const f32x4*)&ub[ks];
                acc += dot4v(wv4, uv4);
            }
            asm volatile("" ::: "memory");
            __builtin_amdgcn_s_barrier();
        }

        // reduce 16 threads per row
#pragma unroll
        for (int m = 8; m >= 1; m >>= 1) acc += __shfl_xor(acc, m, 16);
        if (g == 0) {
            const int row = slab * 16 + r;
            h0[row] = acc + init_b[row];
        }
    }
}

// ============ K_P1: per-chunk (prod dA, local h with h_in=0) =================
__global__ __launch_bounds__(256) void k_p1(const float* __restrict__ dt,
                                            const float* __restrict__ Bm,
                                            const float* __restrict__ u,
                                            const float* __restrict__ A_log,
                                            float* __restrict__ ap,
                                            float* __restrict__ hl) {
    const int t    = threadIdx.x;
    const int c    = blockIdx.x >> 3;
    const int dblk = blockIdx.x & 7;
    const int dd   = t >> 1;
    const int nh   = t & 1;
    const int d    = dblk * 128 + dd;
    float An[8];
#pragma unroll
    for (int n = 0; n < 8; ++n) An[n] = -__expf(A_log[nh * 8 + n]);
    float h[8], p[8];
#pragma unroll
    for (int n = 0; n < 8; ++n) { h[n] = 0.f; p[n] = 1.f; }

    const int l0 = c * T_CHUNK;
    for (int i = 0; i < T_CHUNK; ++i) {
        const int l = l0 + i;
        const float dtld = dt[l * D_DIM + d];
        const float uld  = u[l * D_DIM + d];
        const float4 b0 = *(const float4*)&Bm[l * 16 + nh * 8];
        const float4 b1 = *(const float4*)&Bm[l * 16 + nh * 8 + 4];
        auto body = [&](int n, float bn) {
            const float x = dtld * An[n];
            const float e = __expf(x);
            const float coef = (e - 1.f) * __builtin_amdgcn_rcpf(x + EPS_DISC);
            const float bu = coef * bn * uld;
            p[n] *= e;
            h[n] = fmaf(e, h[n], bu);
        };
        body(0, b0.x); body(1, b0.y); body(2, b0.z); body(3, b0.w);
        body(4, b1.x); body(5, b1.y); body(6, b1.z); body(7, b1.w);
    }
    const int base = c * (D_DIM * N_DIM) + d * 16 + nh * 8;
    *(float4*)&ap[base + 0] = make_float4(p[0], p[1], p[2], p[3]);
    *(float4*)&ap[base + 4] = make_float4(p[4], p[5], p[6], p[7]);
    *(float4*)&hl[base + 0] = make_float4(h[0], h[1], h[2], h[3]);
    *(float4*)&hl[base + 4] = make_float4(h[4], h[5], h[6], h[7]);
}

// ============ K_P2: chunk-level scan (64 steps) ==============================
__global__ __launch_bounds__(64) void k_p2(const float* __restrict__ h0,
                                           float* __restrict__ ap,
                                           const float* __restrict__ hl) {
    const int ch = blockIdx.x * 64 + threadIdx.x;
    float h = h0[ch];
#pragma unroll 8
    for (int c = 0; c < NCHUNK; ++c) {
        const int idx = c * (D_DIM * N_DIM) + ch;
        const float a = ap[idx];
        const float b = hl[idx];
        ap[idx] = h;
        h = fmaf(a, h, b);
    }
}

// ============ K_P3: recompute with carry-in, fused epilogue ==================
__global__ __launch_bounds__(256) void k_p3(const float* __restrict__ dt,
                                            const float* __restrict__ Bm,
                                            const float* __restrict__ Cm,
                                            const float* __restrict__ u,
                                            const float* __restrict__ A_log,
                                            const float* __restrict__ hstart,
                                            const float* __restrict__ D_w,
                                            const float* __restrict__ scale,
                                            float* __restrict__ out) {
    const int t    = threadIdx.x;
    const int c    = blockIdx.x >> 3;
    const int dblk = blockIdx.x & 7;
    const int dd   = t >> 1;
    const int nh   = t & 1;
    const int d    = dblk * 128 + dd;
    float An[8];
#pragma unroll
    for (int n = 0; n < 8; ++n) An[n] = -__expf(A_log[nh * 8 + n]);
    float h[8];
    const int base = c * (D_DIM * N_DIM) + d * 16 + nh * 8;
    {
        float4 h0v = *(const float4*)&hstart[base + 0];
        float4 h1v = *(const float4*)&hstart[base + 4];
        h[0] = h0v.x; h[1] = h0v.y; h[2] = h0v.z; h[3] = h0v.w;
        h[4] = h1v.x; h[5] = h1v.y; h[6] = h1v.z; h[7] = h1v.w;
    }
    const float scl = fmaxf(scale[0], 0.5f);
    const float dw = D_w[d];
    const int l0 = c * T_CHUNK;
    for (int i = 0; i < T_CHUNK; ++i) {
        const int l = l0 + i;
        const float dtld = dt[l * D_DIM + d];
        const float uld  = u[l * D_DIM + d];
        const float4 b0 = *(const float4*)&Bm[l * 16 + nh * 8];
        const float4 b1 = *(const float4*)&Bm[l * 16 + nh * 8 + 4];
        const float4 c0 = *(const float4*)&Cm[l * 16 + nh * 8];
        const float4 c1 = *(const float4*)&Cm[l * 16 + nh * 8 + 4];
        float y = 0.f;
        auto body = [&](int n, float bn, float cn) {
            const float x = dtld * An[n];
            const float e = __expf(x);
            const float coef = (e - 1.f) * __builtin_amdgcn_rcpf(x + EPS_DISC);
            const float bu = coef * bn * uld;
            h[n] = fmaf(e, h[n], bu);
            y = fmaf(cn, h[n], y);
        };
        body(0, b0.x, c0.x); body(1, b0.y, c0.y); body(2, b0.z, c0.z); body(3, b0.w, c0.w);
        body(4, b1.x, c1.x); body(5, b1.y, c1.y); body(6, b1.z, c1.z); body(7, b1.w, c1.w);
        y += __shfl_xor(y, 1);
        if (nh == 0) {
            const float yv = fmaf(dw, uld, y);
            out[l * D_DIM + d] = softplusf(yv) * scl;
        }
    }
}

extern "C" void kernel_launch(void* const* d_in, const int* in_sizes, int n_in,
                              void* d_out, int out_size, void* d_ws, size_t ws_size,
                              hipStream_t stream) {
    const float* u      = (const float*)d_in[0];
    const float* A_log  = (const float*)d_in[1];
    const float* dt_w   = (const float*)d_in[2];
    const float* dt_b   = (const float*)d_in[3];
    const float* B_w    = (const float*)d_in[4];
    const float* B_b    = (const float*)d_in[5];
    const float* C_w    = (const float*)d_in[6];
    const float* C_b    = (const float*)d_in[7];
    const float* D_w    = (const float*)d_in[8];
    const float* scale  = (const float*)d_in[9];
    const float* init_w = (const float*)d_in[10];
    const float* init_b = (const float*)d_in[11];
    float* out = (float*)d_out;

    float* ws = (float*)d_ws;
    float* dt = ws;                        // 2048*1024 = 2097152
    float* Bm = dt + 2097152;              // 32768
    float* Cm = Bm + 32768;                // 32768
    float* h0 = Cm + 32768;                // 16384
    float* ap = h0 + 16384;                // 64*16384 = 1048576
    float* hl = ap + 1048576;              // 1048576

    hipLaunchKernelGGL(k_params, dim3(1536), dim3(256), 0, stream,
                       u, dt_w, dt_b, B_w, B_b, C_w, C_b, init_w, init_b,
                       dt, Bm, Cm, h0);
    hipLaunchKernelGGL(k_p1, dim3(512), dim3(256), 0, stream, dt, Bm, u, A_log, ap, hl);
    hipLaunchKernelGGL(k_p2, dim3(256), dim3(64), 0, stream, h0, ap, hl);
    hipLaunchKernelGGL(k_p3, dim3(512), dim3(256), 0, stream, dt, Bm, Cm, u, A_log, ap, D_w, scale, out);
}